// Round 8
// baseline (220.978 us; speedup 1.0000x reference)
//
#include <hip/hip_runtime.h>
#include <math.h>
#include <limits.h>
#include <string.h>

// Homography warp + bilinear sampling, bit-faithful to the numpy reference:
//  - no FMA contraction (pragma) so products/sums round like np
//  - two IEEE divisions (not reciprocal-multiply)
//  - float->int32 emulates x86 cvttss2si (overflow -> INT_MIN -> clips to 0)
//  - weight/accumulate expression order identical to the reference
//
// Perf history (kernel-only est.; total has ~148 us harness fill overhead):
//  R1 naive/px: 76.6 -> R2 pair-loads + PX=4 STRIDED px/thread: ~38
//  R3 consecutive px + dwordx4 stores: ~42 (REGRESSED: 16B lane stride
//    tripled cache lines touched per gather instruction)
//  R4 strided + all-loads-upfront MLP + 32-bit saddr idx: ~35
//  R5 pk-f32 math + ballot fast path: neutral -> not VALU-bound
//  R6 XCD swizzle: ~43 (REGRESSED: broke dispatch-order L2/L3 locality)
//  R7 LDS store-repack (27 vs 36 VMEM instr/thread): neutral -> stores
//    not binding; gather pipe + imperfect VALU/VMEM overlap is the wall.
//  R8 (this): occupancy over per-wave MLP. All-loads-upfront held 48 VGPRs
//    of data -> ~4 waves/SIMD. Per-channel pipeline (16 data VGPRs peak) +
//    __launch_bounds__(256,8) forces <=64 VGPRs -> 8 waves/SIMD; TLP keeps
//    the TA fed instead of per-wave load depth.

#define SMALL_F 1e-7f
#define EPS_F   1e-6f
#define PX 4

typedef float v2f __attribute__((ext_vector_type(2)));

__device__ __forceinline__ int cvt_f32_i32_x86(float f) {
    // x86 cvttss2si: values >= 2^31 (incl. +inf) give INT_MIN.
    if (f >= 2147483648.0f) return INT_MIN;
    return (int)f;  // input is pre-floored, trunc == floor
}

__global__ void __launch_bounds__(256, 8)
warp_bilinear_kernel(const float* __restrict__ src, const float* __restrict__ Hm,
                     float* __restrict__ out, int B, int h, int w) {
#pragma clang fp contract(off)
    const int y  = blockIdx.y;
    const int b  = blockIdx.z;
    const int tx = threadIdx.x;
    const int xstart = blockIdx.x * (256 * PX) + tx;

    const float* Hb = Hm + (size_t)b * 9;   // block-uniform -> s_load
    const float H0 = Hb[0], H1 = Hb[1], H2 = Hb[2];
    const float H3 = Hb[3], H4 = Hb[4], H5 = Hb[5];
    const float H6 = Hb[6], H7 = Hb[7], H8 = Hb[8];
    const float gy = (float)y;
    // Hoisting the *products* Hj*gy is bit-identical (single rounding each);
    // sums below keep the reference's left-assoc, contraction-off order.
    const float p1 = H1 * gy, p4 = H4 * gy, p7 = H7 * gy;

    unsigned idx0[PX], idx1[PX];            // 32-bit in-plane indices
    v2f wa2[2], wb2[2], wc2[2], wd2[2];
    bool sA[PX], sC[PX], valid[PX];

    // ---- Phase 1: coordinates + weights (packed f32 where ops pair) ----
#pragma unroll
    for (int j = 0; j < 2; ++j) {
        const int ka = 2 * j, kb = 2 * j + 1;
        const int xa = xstart + 256 * ka, xb_ = xstart + 256 * kb;
        valid[ka] = (xa < w); valid[kb] = (xb_ < w);
        v2f gx = { (float)xa, (float)xb_ };
        // einsum row sums: (Hj*gx + Hj1*gy) + Hj2, left-assoc, no FMA.
        v2f w0 = (H0 * gx + p1) + H2;       // v_pk_mul + 2x v_pk_add
        v2f w1 = (H3 * gx + p4) + H5;
        v2f T  = (H6 * gx + p7) + H8;
        float Ta = T[0], Tb = T[1];
        if (!(fabsf(Ta) >= SMALL_F)) Ta = Ta + EPS_F;
        if (!(fabsf(Tb) >= SMALL_F)) Tb = Tb + EPS_F;
        v2f xs = { w0[0] / Ta, w0[1] / Tb };   // IEEE divs, matches np
        v2f ys = { w1[0] / Ta, w1[1] / Tb };

        v2f x0f, x1f, y0f, y1f;
#pragma unroll
        for (int e = 0; e < 2; ++e) {
            const int k = 2 * j + e;
            int x0u = cvt_f32_i32_x86(floorf(xs[e]));
            int y0u = cvt_f32_i32_x86(floorf(ys[e]));
            int x1 = min(max(x0u + 1, 0), w - 1);
            int y1 = min(max(y0u + 1, 0), h - 1);
            int x0 = min(max(x0u, 0), w - 1);
            int y0 = min(max(y0u, 0), h - 1);
            x0f[e] = (float)x0; x1f[e] = (float)x1;
            y0f[e] = (float)y0; y1f[e] = (float)y1;
            // Pair base: taps are {xb, xb+1}; x0,x1 each select one of the
            // two (identical at clipped edges). Selects are bit-exact.
            int xb = min(max(x0u, 0), w - 2);
            sA[k] = (x0 == xb);
            sC[k] = (x1 == xb);
            idx0[k] = (unsigned)(y0 * w + xb);
            idx1[k] = (unsigned)(y1 * w + xb);
        }
        v2f t1 = x1f - xs;                   // (x1f - x)   v_pk_add
        v2f t2 = y1f - ys;                   // (y1f - y)
        v2f t3 = ys - y0f;                   // (y - y0f)
        v2f t4 = xs - x0f;                   // (x - x0f)
        wa2[j] = t1 * t2;                    // v_pk_mul
        wb2[j] = t1 * t3;
        wc2[j] = t4 * t2;
        wd2[j] = t4 * t3;
    }

    const size_t plane = (size_t)h * (size_t)w;
    const float* sb = src + (size_t)b * 3 * plane;
    float* ob = out + (size_t)b * 3 * plane + (size_t)y * (size_t)w;

    const bool fullblock = ((blockIdx.x + 1) * (256 * PX)) <= (unsigned)w;

    if (fullblock) {
        // ---- Phase 2/3: per-channel pipeline (low VGPR, TLP-driven) ----
#pragma unroll
        for (int c = 0; c < 3; ++c) {
            const float* sc = sb + (size_t)c * plane;   // uniform base
            float* oc = ob + (size_t)c * plane;
            float q0[PX][2], q1[PX][2];
#pragma unroll
            for (int k = 0; k < PX; ++k) {
                __builtin_memcpy(q0[k], sc + idx0[k], 8);  // dwordx2
                __builtin_memcpy(q1[k], sc + idx1[k], 8);
            }
#pragma unroll
            for (int j = 0; j < 2; ++j) {
                const int ka = 2 * j, kb = 2 * j + 1;
                v2f Ia = { sA[ka] ? q0[ka][0] : q0[ka][1],
                           sA[kb] ? q0[kb][0] : q0[kb][1] };
                v2f Ic = { sC[ka] ? q0[ka][0] : q0[ka][1],
                           sC[kb] ? q0[kb][0] : q0[kb][1] };
                v2f Ib = { sA[ka] ? q1[ka][0] : q1[ka][1],
                           sA[kb] ? q1[kb][0] : q1[kb][1] };
                v2f Id = { sC[ka] ? q1[ka][0] : q1[ka][1],
                           sC[kb] ? q1[kb][0] : q1[kb][1] };
                // np order: (((wa*Ia + wb*Ib) + wc*Ic) + wd*Id), no FMA
                v2f r = ((wa2[j] * Ia + wb2[j] * Ib) + wc2[j] * Ic) + wd2[j] * Id;
                __builtin_nontemporal_store(r[0], oc + xstart + 256 * ka);
                __builtin_nontemporal_store(r[1], oc + xstart + 256 * kb);
            }
        }
    } else {
        // Tail blocks (w not divisible by 1024): per-pixel scalar path.
#pragma unroll
        for (int c = 0; c < 3; ++c) {
            const float* sc = sb + (size_t)c * plane;
            float* oc = ob + (size_t)c * plane;
#pragma unroll
            for (int k = 0; k < PX; ++k) {
                if (!valid[k]) continue;
                float pr0[2], pr1[2];
                __builtin_memcpy(pr0, sc + idx0[k], 8);
                __builtin_memcpy(pr1, sc + idx1[k], 8);
                float Ia = sA[k] ? pr0[0] : pr0[1];
                float Ic = sC[k] ? pr0[0] : pr0[1];
                float Ib = sA[k] ? pr1[0] : pr1[1];
                float Id = sC[k] ? pr1[0] : pr1[1];
                const int j = k >> 1, e = k & 1;
                float r = ((wa2[j][e] * Ia + wb2[j][e] * Ib) + wc2[j][e] * Ic)
                          + wd2[j][e] * Id;
                __builtin_nontemporal_store(r, oc + xstart + 256 * k);
            }
        }
    }
}

extern "C" void kernel_launch(void* const* d_in, const int* in_sizes, int n_in,
                              void* d_out, int out_size, void* d_ws, size_t ws_size,
                              hipStream_t stream) {
    const float* src = (const float*)d_in[0];
    const float* Hm  = (const float*)d_in[1];
    float* out = (float*)d_out;

    const int B = in_sizes[1] / 9;          // 8
    const int C = 3;
    const size_t plane = (size_t)in_sizes[0] / ((size_t)B * C);
    const int h = 1024;                     // setup_inputs: 1024x1024
    const int w = (int)(plane / h);

    dim3 block(256, 1, 1);
    dim3 grid((w + 256 * PX - 1) / (256 * PX), h, B);
    warp_bilinear_kernel<<<grid, block, 0, stream>>>(src, Hm, out, B, h, w);
}

// Round 9
// 182.534 us; speedup vs baseline: 1.2106x; 1.2106x over previous
//
#include <hip/hip_runtime.h>
#include <math.h>
#include <limits.h>
#include <string.h>

// Homography warp + bilinear sampling, bit-faithful to the numpy reference:
//  - no FMA contraction (pragma) so products/sums round like np
//  - two IEEE divisions (not reciprocal-multiply)
//  - float->int32 emulates x86 cvttss2si (overflow -> INT_MIN -> clips to 0)
//  - weight/accumulate expression order identical to the reference
//
// Perf history (kernel-only est.; total has ~148 us harness fill overhead):
//  R1 naive/px: 76.6 -> R2 pair-loads + PX=4 STRIDED px/thread: ~38
//  R3 consecutive px + dwordx4 stores: ~42 (REGRESSED: 16B lane stride
//    tripled cache lines touched per gather instruction)
//  R4 strided + all-loads-upfront MLP + 32-bit saddr idx: ~35
//  R5 pk-f32 math + ballot fast path: 183.13 total -- BEST
//  R6 XCD swizzle: ~43 (REGRESSED: broke dispatch-order L2/L3 locality)
//  R7 LDS store-repack: neutral -> stores not binding
//  R8 __launch_bounds__(256,8): 221 (REGRESSED: VGPR=32 forced scratch
//    spills -- WRITE_SIZE 96->179 MB, FETCH 11->35 MB. Occupancy was never
//    the limiter.)
//  R9 (this): restore R5 verbatim. Structure sits at the joint floor:
//    6 gathers/px is the algorithmic minimum, IEEE div/clip chain is
//    locked by bit-exactness, stores/L2 locality/occupancy all proven
//    non-binding (R6/R7/R8).

#define SMALL_F 1e-7f
#define EPS_F   1e-6f
#define PX 4

typedef float v2f __attribute__((ext_vector_type(2)));

__device__ __forceinline__ int cvt_f32_i32_x86(float f) {
    // x86 cvttss2si: values >= 2^31 (incl. +inf) give INT_MIN.
    if (f >= 2147483648.0f) return INT_MIN;
    return (int)f;  // input is pre-floored, trunc == floor
}

__global__ void __launch_bounds__(256)
warp_bilinear_kernel(const float* __restrict__ src, const float* __restrict__ Hm,
                     float* __restrict__ out, int B, int h, int w) {
#pragma clang fp contract(off)
    const int y  = blockIdx.y;
    const int b  = blockIdx.z;
    const int tx = threadIdx.x;
    const int xstart = blockIdx.x * (256 * PX) + tx;

    const float* Hb = Hm + (size_t)b * 9;   // block-uniform -> s_load
    const float H0 = Hb[0], H1 = Hb[1], H2 = Hb[2];
    const float H3 = Hb[3], H4 = Hb[4], H5 = Hb[5];
    const float H6 = Hb[6], H7 = Hb[7], H8 = Hb[8];
    const float gy = (float)y;
    // Hoisting the *products* Hj*gy is bit-identical (single rounding each);
    // sums below keep the reference's left-assoc, contraction-off order.
    const float p1 = H1 * gy, p4 = H4 * gy, p7 = H7 * gy;

    unsigned idx0[PX], idx1[PX];            // 32-bit in-plane indices
    v2f wa2[2], wb2[2], wc2[2], wd2[2];
    bool sA[PX], sC[PX], valid[PX];
    bool allvalid = true;

    // ---- Phase 1: coordinates + weights (packed f32 where ops pair) ----
#pragma unroll
    for (int j = 0; j < 2; ++j) {
        const int ka = 2 * j, kb = 2 * j + 1;
        const int xa = xstart + 256 * ka, xb_ = xstart + 256 * kb;
        valid[ka] = (xa < w); valid[kb] = (xb_ < w);
        allvalid &= valid[ka] & valid[kb];
        v2f gx = { (float)xa, (float)xb_ };
        // einsum row sums: (Hj*gx + Hj1*gy) + Hj2, left-assoc, no FMA.
        v2f w0 = (H0 * gx + p1) + H2;       // v_pk_mul + 2x v_pk_add
        v2f w1 = (H3 * gx + p4) + H5;
        v2f T  = (H6 * gx + p7) + H8;
        float Ta = T[0], Tb = T[1];
        if (!(fabsf(Ta) >= SMALL_F)) Ta = Ta + EPS_F;
        if (!(fabsf(Tb) >= SMALL_F)) Tb = Tb + EPS_F;
        v2f xs = { w0[0] / Ta, w0[1] / Tb };   // IEEE divs, matches np
        v2f ys = { w1[0] / Ta, w1[1] / Tb };

        v2f x0f, x1f, y0f, y1f;
#pragma unroll
        for (int e = 0; e < 2; ++e) {
            const int k = 2 * j + e;
            int x0u = cvt_f32_i32_x86(floorf(xs[e]));
            int y0u = cvt_f32_i32_x86(floorf(ys[e]));
            int x1 = min(max(x0u + 1, 0), w - 1);
            int y1 = min(max(y0u + 1, 0), h - 1);
            int x0 = min(max(x0u, 0), w - 1);
            int y0 = min(max(y0u, 0), h - 1);
            x0f[e] = (float)x0; x1f[e] = (float)x1;
            y0f[e] = (float)y0; y1f[e] = (float)y1;
            // Pair base: taps are {xb, xb+1}; x0,x1 each select one of the
            // two (identical at clipped edges). Selects are bit-exact.
            int xb = min(max(x0u, 0), w - 2);
            sA[k] = (x0 == xb);
            sC[k] = (x1 == xb);
            idx0[k] = (unsigned)(y0 * w + xb);
            idx1[k] = (unsigned)(y1 * w + xb);
        }
        v2f t1 = x1f - xs;                   // (x1f - x)   v_pk_add
        v2f t2 = y1f - ys;                   // (y1f - y)
        v2f t3 = ys - y0f;                   // (y - y0f)
        v2f t4 = xs - x0f;                   // (x - x0f)
        wa2[j] = t1 * t2;                    // v_pk_mul
        wb2[j] = t1 * t3;
        wc2[j] = t4 * t2;
        wd2[j] = t4 * t3;
    }

    const size_t plane = (size_t)h * (size_t)w;
    const float* sb = src + (size_t)b * 3 * plane;
    float* ob = out + (size_t)b * 3 * plane + (size_t)y * (size_t)w;

    if (allvalid) {
        // ---- Phase 2: ALL pair-loads before any consumer (max MLP) ----
        float q0[3][PX][2], q1[3][PX][2];
#pragma unroll
        for (int c = 0; c < 3; ++c) {
            const float* sc = sb + (size_t)c * plane;   // uniform base
#pragma unroll
            for (int k = 0; k < PX; ++k) {
                __builtin_memcpy(q0[c][k], sc + idx0[k], 8);  // dwordx2
                __builtin_memcpy(q1[c][k], sc + idx1[k], 8);
            }
        }
        // ---- Phase 3: select (skipped on interior waves), blend, store ----
        bool noxclip = sA[0] & sA[1] & sA[2] & sA[3] &
                       !(sC[0] | sC[1] | sC[2] | sC[3]);
        if (__ballot(noxclip) == ~0ull) {
            // whole wave interior in x: Ia=lo0, Ic=hi0, Ib=lo1, Id=hi1
#pragma unroll
            for (int c = 0; c < 3; ++c) {
                float* oc = ob + (size_t)c * plane;
#pragma unroll
                for (int j = 0; j < 2; ++j) {
                    const int ka = 2 * j, kb = 2 * j + 1;
                    v2f Ia = { q0[c][ka][0], q0[c][kb][0] };
                    v2f Ic = { q0[c][ka][1], q0[c][kb][1] };
                    v2f Ib = { q1[c][ka][0], q1[c][kb][0] };
                    v2f Id = { q1[c][ka][1], q1[c][kb][1] };
                    // np order: (((wa*Ia + wb*Ib) + wc*Ic) + wd*Id), no FMA
                    v2f r = ((wa2[j] * Ia + wb2[j] * Ib) + wc2[j] * Ic) + wd2[j] * Id;
                    __builtin_nontemporal_store(r[0], oc + xstart + 256 * ka);
                    __builtin_nontemporal_store(r[1], oc + xstart + 256 * kb);
                }
            }
        } else {
#pragma unroll
            for (int c = 0; c < 3; ++c) {
                float* oc = ob + (size_t)c * plane;
#pragma unroll
                for (int j = 0; j < 2; ++j) {
                    const int ka = 2 * j, kb = 2 * j + 1;
                    v2f Ia = { sA[ka] ? q0[c][ka][0] : q0[c][ka][1],
                               sA[kb] ? q0[c][kb][0] : q0[c][kb][1] };
                    v2f Ic = { sC[ka] ? q0[c][ka][0] : q0[c][ka][1],
                               sC[kb] ? q0[c][kb][0] : q0[c][kb][1] };
                    v2f Ib = { sA[ka] ? q1[c][ka][0] : q1[c][ka][1],
                               sA[kb] ? q1[c][kb][0] : q1[c][kb][1] };
                    v2f Id = { sC[ka] ? q1[c][ka][0] : q1[c][ka][1],
                               sC[kb] ? q1[c][kb][0] : q1[c][kb][1] };
                    v2f r = ((wa2[j] * Ia + wb2[j] * Ib) + wc2[j] * Ic) + wd2[j] * Id;
                    __builtin_nontemporal_store(r[0], oc + xstart + 256 * ka);
                    __builtin_nontemporal_store(r[1], oc + xstart + 256 * kb);
                }
            }
        }
    } else {
        // Tail blocks (w not divisible by 1024): per-pixel scalar path.
#pragma unroll
        for (int c = 0; c < 3; ++c) {
            const float* sc = sb + (size_t)c * plane;
            float* oc = ob + (size_t)c * plane;
#pragma unroll
            for (int k = 0; k < PX; ++k) {
                if (!valid[k]) continue;
                float pr0[2], pr1[2];
                __builtin_memcpy(pr0, sc + idx0[k], 8);
                __builtin_memcpy(pr1, sc + idx1[k], 8);
                float Ia = sA[k] ? pr0[0] : pr0[1];
                float Ic = sC[k] ? pr0[0] : pr0[1];
                float Ib = sA[k] ? pr1[0] : pr1[1];
                float Id = sC[k] ? pr1[0] : pr1[1];
                const int j = k >> 1, e = k & 1;
                float r = ((wa2[j][e] * Ia + wb2[j][e] * Ib) + wc2[j][e] * Ic)
                          + wd2[j][e] * Id;
                __builtin_nontemporal_store(r, oc + xstart + 256 * k);
            }
        }
    }
}

extern "C" void kernel_launch(void* const* d_in, const int* in_sizes, int n_in,
                              void* d_out, int out_size, void* d_ws, size_t ws_size,
                              hipStream_t stream) {
    const float* src = (const float*)d_in[0];
    const float* Hm  = (const float*)d_in[1];
    float* out = (float*)d_out;

    const int B = in_sizes[1] / 9;          // 8
    const int C = 3;
    const size_t plane = (size_t)in_sizes[0] / ((size_t)B * C);
    const int h = 1024;                     // setup_inputs: 1024x1024
    const int w = (int)(plane / h);

    dim3 block(256, 1, 1);
    dim3 grid((w + 256 * PX - 1) / (256 * PX), h, B);
    warp_bilinear_kernel<<<grid, block, 0, stream>>>(src, Hm, out, B, h, w);
}